// Round 13
// baseline (150.186 us; speedup 1.0000x reference)
//
#include <hip/hip_runtime.h>
#include <hip/hip_bf16.h>

// QMixer forward, MI355X gfx950. fp32 in/out, bf16 MFMA for all matmul blocks.
// B=128 S=128 A=8 En=8 E=16 NFal=32 NFen=16 D=64 Da=128 M=32 H=64.
// Algebra (verified R4): softmax over query axis i cancels per-column-j terms:
//   energy[i][j] = e_i (Wq Wk^T/sqrt(Da)) e_j^T + e_i.(Wq bk)/sqrt(Da)
// R13: (1) single scr buffer (sites serialize through t/energy; wave-private
// in-order DS makes it safe) -> LDS 19.4->14.85 KB/block -> 22 waves/CU;
// (2) all global scalars preloaded before the first FENCE (fences pinned the
// late-epilogue L2 loads behind the whole attention phase).
// MFMA 16x16x32 layouts (HW-verified): A[m=lane&15][k=quad*8+j],
// B[k=quad*8+j][n=lane&15], C/D[row=quad*4+r][col=lane&15].

#define B_   128
#define S_   128
#define BS_  (B_ * S_)
#define INV_S 0.08838834764831845f  // 1/sqrt(128)

typedef short bs8 __attribute__((ext_vector_type(8)));
typedef short bs4 __attribute__((ext_vector_type(4)));
typedef float f4  __attribute__((ext_vector_type(4)));

#define MFMA(a, b, c) __builtin_amdgcn_mfma_f32_16x16x32_bf16((a), (b), (c), 0, 0, 0)
#define LOADB(t) (*(const bs8*)&fb[(size_t)(t) * 512 + lane * 8])
#define FENCE() asm volatile("" ::: "memory")

__device__ __forceinline__ short f2bf(float f) {
    union { float f; unsigned u; } v; v.f = f;
    unsigned r = v.u + 0x7fffu + ((v.u >> 16) & 1u);   // RNE
    return (short)(r >> 16);
}
__device__ __forceinline__ unsigned f2bf2(float lo, float hi) {
    return (unsigned)(unsigned short)f2bf(lo) | ((unsigned)(unsigned short)f2bf(hi) << 16);
}
__device__ __forceinline__ float bf2f_lo(unsigned u) {
    union { unsigned u; float f; } v; v.u = u << 16; return v.f;
}
__device__ __forceinline__ float bf2f_hi(unsigned u) {
    union { unsigned u; float f; } v; v.u = u & 0xffff0000u; return v.f;
}

// ---------------- pack: bf16 B-fragment tiles (unchanged from R12) ----------------
// frag tile = 512 bf16: [lane][j], elem j = W[k = ks*32+quad*8+j][n = n0+l16]
// tiles: 0-7 M | 8-11 W_al | 12-15 W_en(K=16 pad) | 16-31 w1_W1 | 32-35 w1_W2 |
//        36-37 vq col | 38-53 bigW1=[wf_W1|hb_W|v_W1] | 54-57 wf_W2
__global__ __launch_bounds__(64)
void qmix_pack(const float* __restrict__ Wq,   const float* __restrict__ Wk,
               const float* __restrict__ bk,
               const float* __restrict__ W_al, const float* __restrict__ W_en,
               const float* __restrict__ w1_W1, const float* __restrict__ w1_W2,
               const float* __restrict__ wf_W1, const float* __restrict__ hb_W,
               const float* __restrict__ v_W1,  const float* __restrict__ wf_W2,
               short* __restrict__ fb)
{
    const int blk = blockIdx.x, lane = threadIdx.x;
    const int quad = lane >> 4, l16 = lane & 15;
    bs8 v;
    if (blk < 8) {
        const int ks = blk >> 2, n = (blk & 3) * 16 + l16;
        float acc[8] = {0.f,0.f,0.f,0.f,0.f,0.f,0.f,0.f};
        const float4* wk4 = (const float4*)(Wk + n * 128);
        for (int t4 = 0; t4 < 32; ++t4) {
            const float4 wk = wk4[t4];
            #pragma unroll
            for (int j = 0; j < 8; ++j) {
                const float4 wq = *(const float4*)(Wq + (ks * 32 + quad * 8 + j) * 128 + t4 * 4);
                acc[j] += wq.x * wk.x + wq.y * wk.y + wq.z * wk.z + wq.w * wk.w;
            }
        }
        #pragma unroll
        for (int j = 0; j < 8; ++j) v[j] = f2bf(acc[j] * INV_S);
    } else if (blk < 16) {
        const bool en = (blk >= 12);
        const float* W = en ? W_en : W_al;
        const int Krows = en ? 16 : 32;
        const int n = ((blk - (en ? 12 : 8)) & 3) * 16 + l16;
        #pragma unroll
        for (int j = 0; j < 8; ++j) {
            const int k = quad * 8 + j;
            v[j] = (k < Krows) ? f2bf(W[k * 64 + n]) : (short)0;
        }
    } else if (blk < 32) {
        const int t = blk - 16, ks = t >> 2, n = (t & 3) * 16 + l16;
        #pragma unroll
        for (int j = 0; j < 8; ++j)
            v[j] = f2bf(w1_W1[(ks * 32 + quad * 8 + j) * 64 + n]);
    } else if (blk < 36) {
        const int t = blk - 32, ks = t >> 1, n = (t & 1) * 16 + l16;
        #pragma unroll
        for (int j = 0; j < 8; ++j)
            v[j] = f2bf(w1_W2[(ks * 32 + quad * 8 + j) * 32 + n]);
    } else if (blk < 38) {
        const int ks = blk - 36;
        float acc[8] = {0.f,0.f,0.f,0.f,0.f,0.f,0.f,0.f};
        const float4* bk4 = (const float4*)bk;
        for (int t4 = 0; t4 < 32; ++t4) {
            const float4 b = bk4[t4];
            #pragma unroll
            for (int j = 0; j < 8; ++j) {
                const float4 wq = *(const float4*)(Wq + (ks * 32 + quad * 8 + j) * 128 + t4 * 4);
                acc[j] += wq.x * b.x + wq.y * b.y + wq.z * b.z + wq.w * b.w;
            }
        }
        #pragma unroll
        for (int j = 0; j < 8; ++j)
            v[j] = (l16 == 0) ? f2bf(acc[j] * INV_S) : (short)0;
    } else if (blk < 54) {
        const int t = blk - 38, ks = t >> 3, n = (t & 7) * 16 + l16;
        #pragma unroll
        for (int j = 0; j < 8; ++j) {
            const int k = ks * 32 + quad * 8 + j;
            float w;
            if (n < 64)       w = wf_W1[k * 64 + n];
            else if (n < 96)  w = hb_W[k * 32 + (n - 64)];
            else              w = v_W1[k * 32 + (n - 96)];
            v[j] = f2bf(w);
        }
    } else {
        const int t = blk - 54, ks = t >> 1, n = (t & 1) * 16 + l16;
        #pragma unroll
        for (int j = 0; j < 8; ++j)
            v[j] = f2bf(wf_W2[(ks * 32 + quad * 8 + j) * 32 + n]);
    }
    *(bs8*)&fb[(size_t)blk * 512 + lane * 8] = v;
}

// ---------------- main: 2 waves/block, 2 sites/wave, zero barriers ----------------
struct __align__(16) WaveLds {
    short ent[2][16][72];  // persistent bf16 embeds (144B rows)
    short scr[16][72];     // t^T (per site, sequential); later hall^T
    short aoutb[2][64];
    short hb16[2][64];
};

__global__ __launch_bounds__(128, 4)
void qmix_main(const float* __restrict__ agent_qs,
               const float* __restrict__ ally, const float* __restrict__ enemy,
               const float* __restrict__ b_al, const float* __restrict__ b_en,
               const float* __restrict__ w1_b1, const float* __restrict__ w1_b2,
               const float* __restrict__ wf_b1, const float* __restrict__ wf_b2,
               const float* __restrict__ hb_b,  const float* __restrict__ v_b1,
               const float* __restrict__ v_W2,  const float* __restrict__ v_b2,
               const short* __restrict__ fb,
               float* __restrict__ out)
{
    const int w    = threadIdx.x >> 6;
    const int lane = threadIdx.x & 63;
    const int quad = lane >> 4, l16 = lane & 15;
    const int half = lane >> 5;
    const int qh   = quad & 1;
    const int siteA = blockIdx.x * 4 + w * 2;
    const int m32  = lane & 31;

    __shared__ WaveLds lds[2];
    WaveLds& L = lds[w];

    // ---- preload ALL epilogue globals before the first fence (latency overlap) ----
    const float4 qsv4  = *(const float4*)&agent_qs[(size_t)(siteA + half) * 8 + qh * 4];
    const float  wfb2m = wf_b2[m32];
    const float  hbbm  = hb_b[m32];
    const float  vb1m  = v_b1[m32];
    const float  vW2m  = v_W2[m32];
    const float  vb2   = v_b2[0];
    const float  w1b2a = w1_b2[l16];
    const float  w1b2b = w1_b2[16 + l16];
    const float  wfb1a = wf_b1[(qh * 2 + 0) * 16 + l16];
    const float  wfb1b = wf_b1[(qh * 2 + 1) * 16 + l16];

    unsigned encb[2][4][2];   // packed bf16 fp-embeds: [site][n0t][pair of rows]

    // ---- encoders per site: D rows 0-7 ally, 8-15 enemy ----
    #pragma unroll
    for (int s = 0; s < 2; ++s) {
        const int site = siteA + s;
        bs8 a_al = {0,0,0,0,0,0,0,0}, a_en = {0,0,0,0,0,0,0,0};
        if (l16 < 8) {
            const float* pa = ally + ((size_t)l16 * BS_ + site) * 32 + quad * 8;
            const float4 f0 = *(const float4*)pa, f1 = *(const float4*)(pa + 4);
            a_al[0]=f2bf(f0.x); a_al[1]=f2bf(f0.y); a_al[2]=f2bf(f0.z); a_al[3]=f2bf(f0.w);
            a_al[4]=f2bf(f1.x); a_al[5]=f2bf(f1.y); a_al[6]=f2bf(f1.z); a_al[7]=f2bf(f1.w);
        } else if (quad < 2) {
            const float* pe = enemy + ((size_t)(l16 - 8) * BS_ + site) * 16 + quad * 8;
            const float4 f0 = *(const float4*)pe, f1 = *(const float4*)(pe + 4);
            a_en[0]=f2bf(f0.x); a_en[1]=f2bf(f0.y); a_en[2]=f2bf(f0.z); a_en[3]=f2bf(f0.w);
            a_en[4]=f2bf(f1.x); a_en[5]=f2bf(f1.y); a_en[6]=f2bf(f1.z); a_en[7]=f2bf(f1.w);
        }
        #pragma unroll
        for (int n0t = 0; n0t < 4; ++n0t) {
            f4 acc = {0.f, 0.f, 0.f, 0.f};
            acc = MFMA(a_al, LOADB(8 + n0t), acc);
            acc = MFMA(a_en, LOADB(12 + n0t), acc);
            const int d = n0t * 16 + l16;
            const float bal = b_al[d], ben = b_en[d];
            float vv[4];
            #pragma unroll
            for (int r = 0; r < 4; ++r) {
                const int row = quad * 4 + r;
                vv[r] = acc[r] + (row < 8 ? bal : ben);
                L.ent[s][row][d] = f2bf(vv[r]);
            }
            encb[s][n0t][0] = f2bf2(vv[0], vv[1]);
            encb[s][n0t][1] = f2bf2(vv[2], vv[3]);
        }
    }
    FENCE();

    // ---- per-site A-frags of ent (also B-frags of ent^T) ----
    bs8 ae0s[2], ae1s[2];
    #pragma unroll
    for (int s = 0; s < 2; ++s) {
        ae0s[s] = *(const bs8*)&L.ent[s][l16][quad * 8];
        ae1s[s] = *(const bs8*)&L.ent[s][l16][32 + quad * 8];
    }

    // ---- per site (sequential through single scr): t^T, energy, softmax, aout ----
    #pragma unroll
    for (int s = 0; s < 2; ++s) {
        // t^T = M^T @ ent^T (A = M tiles reused; b64 row-contiguous writes)
        f4 pq = {0.f, 0.f, 0.f, 0.f};
        pq = MFMA(ae0s[s], LOADB(36), pq);
        pq = MFMA(ae1s[s], LOADB(37), pq);
        #pragma unroll
        for (int mdt = 0; mdt < 4; ++mdt) {
            f4 acc = {0.f, 0.f, 0.f, 0.f};
            acc = MFMA(LOADB(0 + mdt), ae0s[s], acc);
            acc = MFMA(LOADB(4 + mdt), ae1s[s], acc);
            bs4 tv;
            #pragma unroll
            for (int r = 0; r < 4; ++r) tv[r] = f2bf(acc[r]);
            *(bs4*)&L.scr[l16][mdt * 16 + quad * 4] = tv;
        }
        FENCE();

        // energy + softmax (no max-sub; |energy|<<1) + attn_out
        f4 eacc = {0.f, 0.f, 0.f, 0.f};
        {
            const bs8 at0 = *(const bs8*)&L.scr[l16][quad * 8];
            const bs8 at1 = *(const bs8*)&L.scr[l16][32 + quad * 8];
            eacc = MFMA(at0, ae0s[s], eacc);
            eacc = MFMA(at1, ae1s[s], eacc);
            const int src = lane & 48;
            #pragma unroll
            for (int r = 0; r < 4; ++r) eacc[r] += __shfl(pq[r], src, 64);
        }
        float er[4], csum = 0.f;
        #pragma unroll
        for (int r = 0; r < 4; ++r) { er[r] = __expf(eacc[r]); csum += er[r]; }
        csum += __shfl_xor(csum, 16, 64);
        csum += __shfl_xor(csum, 32, 64);
        const float inv = 1.f / csum;
        float amean[4];
        #pragma unroll
        for (int r = 0; r < 4; ++r) {
            float p = er[r] * inv;
            p += __shfl_xor(p, 1, 64);
            p += __shfl_xor(p, 2, 64);
            p += __shfl_xor(p, 4, 64);
            p += __shfl_xor(p, 8, 64);
            amean[r] = p * (1.f / 16.f);
        }
        float sel = 0.f;
        #pragma unroll
        for (int n0t = 0; n0t < 4; ++n0t) {
            float ap = amean[0] * bf2f_lo(encb[s][n0t][0])
                     + amean[1] * bf2f_hi(encb[s][n0t][0])
                     + amean[2] * bf2f_lo(encb[s][n0t][1])
                     + amean[3] * bf2f_hi(encb[s][n0t][1]);
            ap += __shfl_xor(ap, 16, 64);
            ap += __shfl_xor(ap, 32, 64);
            sel = (n0t == quad) ? ap : sel;
        }
        L.aoutb[s][quad * 16 + l16] = f2bf(sel);
        FENCE();
    }

    // ---- stacked aout + agent A/B frags ----
    const short* aoP = L.aoutb[l16 >> 3];
    const bs8 aab0 = *(const bs8*)&aoP[quad * 8];
    const bs8 aab1 = *(const bs8*)&aoP[32 + quad * 8];
    const short (*entP)[72] = (l16 < 8) ? L.ent[0] : L.ent[1];
    const bs8 ag0 = *(const bs8*)&entP[l16 & 7][quad * 8];
    const bs8 ag1 = *(const bs8*)&entP[l16 & 7][32 + quad * 8];

    // ---- pass1: x = aout @ [wf_W1 | hb_W | v_W1], both sites stacked ----
    float xm[8];
    #pragma unroll
    for (int n0t = 0; n0t < 8; ++n0t) {
        f4 acc = {0.f, 0.f, 0.f, 0.f};
        acc = MFMA(aab0, LOADB(38 + n0t), acc);
        acc = MFMA(aab1, LOADB(46 + n0t), acc);
        xm[n0t] = acc[0];   // rows within a site identical
    }
    L.hb16[half][(qh * 2 + 0) * 16 + l16] = f2bf(fmaxf(xm[qh * 2 + 0] + wfb1a, 0.f));
    L.hb16[half][(qh * 2 + 1) * 16 + l16] = f2bf(fmaxf(xm[qh * 2 + 1] + wfb1b, 0.f));
    const float b1m = xm[4 + qh] + hbbm;
    const float hv  = fmaxf(xm[6 + qh] + vb1m, 0.f) * vW2m;
    FENCE();

    // ---- wf layer2, both sites stacked ----
    float wfm;
    {
        const short* hfP = L.hb16[l16 >> 3];
        const bs8 hf0 = *(const bs8*)&hfP[quad * 8];
        const bs8 hf1 = *(const bs8*)&hfP[32 + quad * 8];
        f4 acc0 = {0.f, 0.f, 0.f, 0.f};
        acc0 = MFMA(hf0, LOADB(54), acc0);
        acc0 = MFMA(hf1, LOADB(56), acc0);
        f4 acc1 = {0.f, 0.f, 0.f, 0.f};
        acc1 = MFMA(hf0, LOADB(55), acc1);
        acc1 = MFMA(hf1, LOADB(57), acc1);
        wfm = fabsf((qh ? acc1[0] : acc0[0]) + wfb2m);
    }

    // ---- hall^T = w1_W1^T @ emi^T (A = w1_W1 tiles reused; b64 writes) ----
    #pragma unroll
    for (int mt = 0; mt < 4; ++mt) {
        f4 acc = {0.f, 0.f, 0.f, 0.f};
        acc = MFMA(LOADB(16 + mt),      aab0, acc);
        acc = MFMA(LOADB(16 + 4 + mt),  aab1, acc);
        acc = MFMA(LOADB(16 + 8 + mt),  ag0,  acc);
        acc = MFMA(LOADB(16 + 12 + mt), ag1,  acc);
        const float4 b1v4 = *(const float4*)&w1_b1[mt * 16 + quad * 4];
        bs4 hw;
        hw[0] = f2bf(fmaxf(acc[0] + b1v4.x, 0.f));
        hw[1] = f2bf(fmaxf(acc[1] + b1v4.y, 0.f));
        hw[2] = f2bf(fmaxf(acc[2] + b1v4.z, 0.f));
        hw[3] = f2bf(fmaxf(acc[3] + b1v4.w, 0.f));
        *(bs4*)&L.scr[l16][mt * 16 + quad * 4] = hw;
    }
    FENCE();

    // ---- hypernet L2 + mixing partials (rows = stacked agents) ----
    float pm;
    {
        const bs8 ha0 = *(const bs8*)&L.scr[l16][quad * 8];
        const bs8 ha1 = *(const bs8*)&L.scr[l16][32 + quad * 8];
        float p0 = 0.f, p1 = 0.f;
        #pragma unroll
        for (int n0t = 0; n0t < 2; ++n0t) {
            f4 acc = {0.f, 0.f, 0.f, 0.f};
            acc = MFMA(ha0, LOADB(32 + n0t), acc);
            acc = MFMA(ha1, LOADB(34 + n0t), acc);
            const float b2v = n0t ? w1b2b : w1b2a;
            float p = qsv4.x * fabsf(acc[0] + b2v) + qsv4.y * fabsf(acc[1] + b2v)
                    + qsv4.z * fabsf(acc[2] + b2v) + qsv4.w * fabsf(acc[3] + b2v);
            if (n0t == 0) p0 = p; else p1 = p;
        }
        p0 += __shfl_xor(p0, 16, 64);
        p1 += __shfl_xor(p1, 16, 64);
        pm = qh ? p1 : p0;
    }

    // ---- elu, mix (+v partial), half-reduce ----
    float hp = pm + b1m;
    hp = (hp > 0.f) ? hp : (__expf(hp) - 1.f);
    float contrib = hp * wfm + hv;
    contrib += __shfl_xor(contrib, 1, 64);
    contrib += __shfl_xor(contrib, 2, 64);
    contrib += __shfl_xor(contrib, 4, 64);
    contrib += __shfl_xor(contrib, 8, 64);
    contrib += __shfl_xor(contrib, 16, 64);
    if ((lane & 31) == 0)
        out[siteA + half] = contrib + vb2;
}

extern "C" void kernel_launch(void* const* d_in, const int* in_sizes, int n_in,
                              void* d_out, int out_size, void* d_ws, size_t ws_size,
                              hipStream_t stream) {
    const float* p[25];
    for (int i = 0; i < 25; ++i) p[i] = (const float*)d_in[i];
    // 0 agent_qs 1 ally 2 enemy 3 W_al 4 b_al 5 W_en 6 b_en 7 Wq 8 bq 9 Wk 10 bk
    // 11 w1_W1 12 w1_b1 13 w1_W2 14 w1_b2 15 wf_W1 16 wf_b1 17 wf_W2 18 wf_b2
    // 19 hb_W 20 hb_b 21 v_W1 22 v_b1 23 v_W2 24 v_b2
    short* fb = (short*)d_ws;   // 58 tiles * 512 bf16 = 59392 B

    qmix_pack<<<58, 64, 0, stream>>>(p[7], p[9], p[10], p[3], p[5],
                                     p[11], p[13], p[15], p[19], p[21], p[17], fb);
    qmix_main<<<BS_ / 4, 128, 0, stream>>>(
        p[0], p[1], p[2], p[4], p[6], p[12], p[14],
        p[16], p[18], p[20], p[22], p[23], p[24],
        fb, (float*)d_out);
}

// Round 14
// 146.359 us; speedup vs baseline: 1.0261x; 1.0261x over previous
//
#include <hip/hip_runtime.h>
#include <hip/hip_bf16.h>

// QMixer forward, MI355X gfx950. fp32 in/out, bf16 MFMA for all matmul blocks.
// B=128 S=128 A=8 En=8 E=16 NFal=32 NFen=16 D=64 Da=128 M=32 H=64.
// Algebra (verified R4): softmax over query axis i cancels per-column-j terms:
//   energy[i][j] = e_i (Wq Wk^T/sqrt(Da)) e_j^T + e_i.(Wq bk)/sqrt(Da)
// R14 = R12 dual-scr (best ILP) + R13 global-scalar preloads + hardware
// packed bf16 converts (v_cvt_pk_bf16_f32): ~140 f2bf chains (~550 VALU instr
// on the critical path) -> ~70 packed converts.
// MFMA 16x16x32 layouts (HW-verified): A[m=lane&15][k=quad*8+j],
// B[k=quad*8+j][n=lane&15], C/D[row=quad*4+r][col=lane&15].

#define B_   128
#define S_   128
#define BS_  (B_ * S_)
#define INV_S 0.08838834764831845f  // 1/sqrt(128)

typedef short bs8 __attribute__((ext_vector_type(8)));
typedef float f4  __attribute__((ext_vector_type(4)));

#define MFMA(a, b, c) __builtin_amdgcn_mfma_f32_16x16x32_bf16((a), (b), (c), 0, 0, 0)
#define LOADB(t) (*(const bs8*)&fb[(size_t)(t) * 512 + lane * 8])
#define FENCE() asm volatile("" ::: "memory")

__device__ __forceinline__ short f2bf(float f) {
    union { float f; unsigned u; } v; v.f = f;
    unsigned r = v.u + 0x7fffu + ((v.u >> 16) & 1u);   // RNE
    return (short)(r >> 16);
}

#if __has_builtin(__builtin_amdgcn_cvt_pk_bf16_f32)
typedef __bf16 bf2v __attribute__((ext_vector_type(2)));
__device__ __forceinline__ unsigned cvtpk(float lo, float hi) {
    bf2v r = __builtin_amdgcn_cvt_pk_bf16_f32(lo, hi);
    union { bf2v b; unsigned u; } v; v.b = r; return v.u;
}
#else
__device__ __forceinline__ unsigned cvtpk(float lo, float hi) {
    return (unsigned)(unsigned short)f2bf(lo)
         | ((unsigned)(unsigned short)f2bf(hi) << 16);
}
#endif

__device__ __forceinline__ float bf2f_lo(unsigned u) {
    union { unsigned u; float f; } v; v.u = u << 16; return v.f;
}
__device__ __forceinline__ float bf2f_hi(unsigned u) {
    union { unsigned u; float f; } v; v.u = u & 0xffff0000u; return v.f;
}

// ---------------- pack: bf16 B-fragment tiles (unchanged from R12) ----------------
// frag tile = 512 bf16: [lane][j], elem j = W[k = ks*32+quad*8+j][n = n0+l16]
// tiles: 0-7 M | 8-11 W_al | 12-15 W_en(K=16 pad) | 16-31 w1_W1 | 32-35 w1_W2 |
//        36-37 vq col | 38-53 bigW1=[wf_W1|hb_W|v_W1] | 54-57 wf_W2
__global__ __launch_bounds__(64)
void qmix_pack(const float* __restrict__ Wq,   const float* __restrict__ Wk,
               const float* __restrict__ bk,
               const float* __restrict__ W_al, const float* __restrict__ W_en,
               const float* __restrict__ w1_W1, const float* __restrict__ w1_W2,
               const float* __restrict__ wf_W1, const float* __restrict__ hb_W,
               const float* __restrict__ v_W1,  const float* __restrict__ wf_W2,
               short* __restrict__ fb)
{
    const int blk = blockIdx.x, lane = threadIdx.x;
    const int quad = lane >> 4, l16 = lane & 15;
    bs8 v;
    if (blk < 8) {
        const int ks = blk >> 2, n = (blk & 3) * 16 + l16;
        float acc[8] = {0.f,0.f,0.f,0.f,0.f,0.f,0.f,0.f};
        const float4* wk4 = (const float4*)(Wk + n * 128);
        for (int t4 = 0; t4 < 32; ++t4) {
            const float4 wk = wk4[t4];
            #pragma unroll
            for (int j = 0; j < 8; ++j) {
                const float4 wq = *(const float4*)(Wq + (ks * 32 + quad * 8 + j) * 128 + t4 * 4);
                acc[j] += wq.x * wk.x + wq.y * wk.y + wq.z * wk.z + wq.w * wk.w;
            }
        }
        #pragma unroll
        for (int j = 0; j < 8; ++j) v[j] = f2bf(acc[j] * INV_S);
    } else if (blk < 16) {
        const bool en = (blk >= 12);
        const float* W = en ? W_en : W_al;
        const int Krows = en ? 16 : 32;
        const int n = ((blk - (en ? 12 : 8)) & 3) * 16 + l16;
        #pragma unroll
        for (int j = 0; j < 8; ++j) {
            const int k = quad * 8 + j;
            v[j] = (k < Krows) ? f2bf(W[k * 64 + n]) : (short)0;
        }
    } else if (blk < 32) {
        const int t = blk - 16, ks = t >> 2, n = (t & 3) * 16 + l16;
        #pragma unroll
        for (int j = 0; j < 8; ++j)
            v[j] = f2bf(w1_W1[(ks * 32 + quad * 8 + j) * 64 + n]);
    } else if (blk < 36) {
        const int t = blk - 32, ks = t >> 1, n = (t & 1) * 16 + l16;
        #pragma unroll
        for (int j = 0; j < 8; ++j)
            v[j] = f2bf(w1_W2[(ks * 32 + quad * 8 + j) * 32 + n]);
    } else if (blk < 38) {
        const int ks = blk - 36;
        float acc[8] = {0.f,0.f,0.f,0.f,0.f,0.f,0.f,0.f};
        const float4* bk4 = (const float4*)bk;
        for (int t4 = 0; t4 < 32; ++t4) {
            const float4 b = bk4[t4];
            #pragma unroll
            for (int j = 0; j < 8; ++j) {
                const float4 wq = *(const float4*)(Wq + (ks * 32 + quad * 8 + j) * 128 + t4 * 4);
                acc[j] += wq.x * b.x + wq.y * b.y + wq.z * b.z + wq.w * b.w;
            }
        }
        #pragma unroll
        for (int j = 0; j < 8; ++j)
            v[j] = (l16 == 0) ? f2bf(acc[j] * INV_S) : (short)0;
    } else if (blk < 54) {
        const int t = blk - 38, ks = t >> 3, n = (t & 7) * 16 + l16;
        #pragma unroll
        for (int j = 0; j < 8; ++j) {
            const int k = ks * 32 + quad * 8 + j;
            float w;
            if (n < 64)       w = wf_W1[k * 64 + n];
            else if (n < 96)  w = hb_W[k * 32 + (n - 64)];
            else              w = v_W1[k * 32 + (n - 96)];
            v[j] = f2bf(w);
        }
    } else {
        const int t = blk - 54, ks = t >> 1, n = (t & 1) * 16 + l16;
        #pragma unroll
        for (int j = 0; j < 8; ++j)
            v[j] = f2bf(wf_W2[(ks * 32 + quad * 8 + j) * 32 + n]);
    }
    *(bs8*)&fb[(size_t)blk * 512 + lane * 8] = v;
}

// ---------------- main: 2 waves/block, 2 sites/wave, zero barriers ----------------
struct __align__(16) WaveLds {
    short ent[2][16][72];  // persistent bf16 embeds (144B rows)
    short scr[2][16][72];  // t^T per site; scr[0] later = hall^T
    short aoutb[2][64];
    short hb16[2][64];
};

__global__ __launch_bounds__(128, 4)
void qmix_main(const float* __restrict__ agent_qs,
               const float* __restrict__ ally, const float* __restrict__ enemy,
               const float* __restrict__ b_al, const float* __restrict__ b_en,
               const float* __restrict__ w1_b1, const float* __restrict__ w1_b2,
               const float* __restrict__ wf_b1, const float* __restrict__ wf_b2,
               const float* __restrict__ hb_b,  const float* __restrict__ v_b1,
               const float* __restrict__ v_W2,  const float* __restrict__ v_b2,
               const short* __restrict__ fb,
               float* __restrict__ out)
{
    const int w    = threadIdx.x >> 6;
    const int lane = threadIdx.x & 63;
    const int quad = lane >> 4, l16 = lane & 15;
    const int half = lane >> 5;
    const int qh   = quad & 1;
    const int siteA = blockIdx.x * 4 + w * 2;
    const int m32  = lane & 31;

    __shared__ WaveLds lds[2];
    WaveLds& L = lds[w];

    // ---- preload ALL epilogue globals before the first fence ----
    const float4 qsv4  = *(const float4*)&agent_qs[(size_t)(siteA + half) * 8 + qh * 4];
    const float  wfb2m = wf_b2[m32];
    const float  hbbm  = hb_b[m32];
    const float  vb1m  = v_b1[m32];
    const float  vW2m  = v_W2[m32];
    const float  vb2   = v_b2[0];
    const float  w1b2a = w1_b2[l16];
    const float  w1b2b = w1_b2[16 + l16];
    const float  wfb1a = wf_b1[(qh * 2 + 0) * 16 + l16];
    const float  wfb1b = wf_b1[(qh * 2 + 1) * 16 + l16];

    unsigned encb[2][4][2];   // packed bf16 fp-embeds: [site][n0t][row pair]

    // ---- encoders per site: D rows 0-7 ally, 8-15 enemy ----
    #pragma unroll
    for (int s = 0; s < 2; ++s) {
        const int site = siteA + s;
        union { bs8 v; unsigned u[4]; } ca, ce;
        ca.u[0] = ca.u[1] = ca.u[2] = ca.u[3] = 0u;
        ce.u[0] = ce.u[1] = ce.u[2] = ce.u[3] = 0u;
        if (l16 < 8) {
            const float* pa = ally + ((size_t)l16 * BS_ + site) * 32 + quad * 8;
            const float4 f0 = *(const float4*)pa, f1 = *(const float4*)(pa + 4);
            ca.u[0] = cvtpk(f0.x, f0.y); ca.u[1] = cvtpk(f0.z, f0.w);
            ca.u[2] = cvtpk(f1.x, f1.y); ca.u[3] = cvtpk(f1.z, f1.w);
        } else if (quad < 2) {
            const float* pe = enemy + ((size_t)(l16 - 8) * BS_ + site) * 16 + quad * 8;
            const float4 f0 = *(const float4*)pe, f1 = *(const float4*)(pe + 4);
            ce.u[0] = cvtpk(f0.x, f0.y); ce.u[1] = cvtpk(f0.z, f0.w);
            ce.u[2] = cvtpk(f1.x, f1.y); ce.u[3] = cvtpk(f1.z, f1.w);
        }
        #pragma unroll
        for (int n0t = 0; n0t < 4; ++n0t) {
            f4 acc = {0.f, 0.f, 0.f, 0.f};
            acc = MFMA(ca.v, LOADB(8 + n0t), acc);
            acc = MFMA(ce.v, LOADB(12 + n0t), acc);
            const int d = n0t * 16 + l16;
            const float bal = b_al[d], ben = b_en[d];
            const float bsel = (quad < 2) ? bal : ben;   // rows 0-7 vs 8-15
            const unsigned p01 = cvtpk(acc[0] + bsel, acc[1] + bsel);
            const unsigned p23 = cvtpk(acc[2] + bsel, acc[3] + bsel);
            L.ent[s][quad * 4 + 0][d] = (short)p01;
            L.ent[s][quad * 4 + 1][d] = (short)(p01 >> 16);
            L.ent[s][quad * 4 + 2][d] = (short)p23;
            L.ent[s][quad * 4 + 3][d] = (short)(p23 >> 16);
            encb[s][n0t][0] = p01;
            encb[s][n0t][1] = p23;
        }
    }
    FENCE();

    // ---- per-site A-frags of ent (also B-frags of ent^T) ----
    bs8 ae0s[2], ae1s[2];
    #pragma unroll
    for (int s = 0; s < 2; ++s) {
        ae0s[s] = *(const bs8*)&L.ent[s][l16][quad * 8];
        ae1s[s] = *(const bs8*)&L.ent[s][l16][32 + quad * 8];
    }

    // ---- t^T = M^T @ ent^T, both sites (dual scr: full ILP) ----
    f4 pqs[2];
    #pragma unroll
    for (int s = 0; s < 2; ++s) {
        f4 pq = {0.f, 0.f, 0.f, 0.f};
        pq = MFMA(ae0s[s], LOADB(36), pq);
        pq = MFMA(ae1s[s], LOADB(37), pq);
        pqs[s] = pq;
        #pragma unroll
        for (int mdt = 0; mdt < 4; ++mdt) {
            f4 acc = {0.f, 0.f, 0.f, 0.f};
            acc = MFMA(LOADB(0 + mdt), ae0s[s], acc);
            acc = MFMA(LOADB(4 + mdt), ae1s[s], acc);
            uint2 tv;
            tv.x = cvtpk(acc[0], acc[1]);
            tv.y = cvtpk(acc[2], acc[3]);
            *(uint2*)&L.scr[s][l16][mdt * 16 + quad * 4] = tv;
        }
    }
    FENCE();

    // ---- energy + softmax (no max-sub; |energy|<<1) + attn_out per site ----
    #pragma unroll
    for (int s = 0; s < 2; ++s) {
        f4 eacc = {0.f, 0.f, 0.f, 0.f};
        {
            const bs8 at0 = *(const bs8*)&L.scr[s][l16][quad * 8];
            const bs8 at1 = *(const bs8*)&L.scr[s][l16][32 + quad * 8];
            eacc = MFMA(at0, ae0s[s], eacc);
            eacc = MFMA(at1, ae1s[s], eacc);
            const int src = lane & 48;
            #pragma unroll
            for (int r = 0; r < 4; ++r) eacc[r] += __shfl(pqs[s][r], src, 64);
        }
        float er[4], csum = 0.f;
        #pragma unroll
        for (int r = 0; r < 4; ++r) { er[r] = __expf(eacc[r]); csum += er[r]; }
        csum += __shfl_xor(csum, 16, 64);
        csum += __shfl_xor(csum, 32, 64);
        const float inv = 1.f / csum;
        float amean[4];
        #pragma unroll
        for (int r = 0; r < 4; ++r) {
            float p = er[r] * inv;
            p += __shfl_xor(p, 1, 64);
            p += __shfl_xor(p, 2, 64);
            p += __shfl_xor(p, 4, 64);
            p += __shfl_xor(p, 8, 64);
            amean[r] = p * (1.f / 16.f);
        }
        float sel = 0.f;
        #pragma unroll
        for (int n0t = 0; n0t < 4; ++n0t) {
            float ap = amean[0] * bf2f_lo(encb[s][n0t][0])
                     + amean[1] * bf2f_hi(encb[s][n0t][0])
                     + amean[2] * bf2f_lo(encb[s][n0t][1])
                     + amean[3] * bf2f_hi(encb[s][n0t][1]);
            ap += __shfl_xor(ap, 16, 64);
            ap += __shfl_xor(ap, 32, 64);
            sel = (n0t == quad) ? ap : sel;
        }
        L.aoutb[s][quad * 16 + l16] = (short)cvtpk(sel, sel);
    }
    FENCE();

    // ---- stacked aout + agent A/B frags ----
    const short* aoP = L.aoutb[l16 >> 3];
    const bs8 aab0 = *(const bs8*)&aoP[quad * 8];
    const bs8 aab1 = *(const bs8*)&aoP[32 + quad * 8];
    const short (*entP)[72] = (l16 < 8) ? L.ent[0] : L.ent[1];
    const bs8 ag0 = *(const bs8*)&entP[l16 & 7][quad * 8];
    const bs8 ag1 = *(const bs8*)&entP[l16 & 7][32 + quad * 8];

    // ---- pass1: x = aout @ [wf_W1 | hb_W | v_W1], both sites stacked ----
    float xm[8];
    #pragma unroll
    for (int n0t = 0; n0t < 8; ++n0t) {
        f4 acc = {0.f, 0.f, 0.f, 0.f};
        acc = MFMA(aab0, LOADB(38 + n0t), acc);
        acc = MFMA(aab1, LOADB(46 + n0t), acc);
        xm[n0t] = acc[0];   // rows within a site identical
    }
    {
        const unsigned hpk = cvtpk(fmaxf(xm[qh * 2 + 0] + wfb1a, 0.f),
                                   fmaxf(xm[qh * 2 + 1] + wfb1b, 0.f));
        L.hb16[half][(qh * 2 + 0) * 16 + l16] = (short)hpk;
        L.hb16[half][(qh * 2 + 1) * 16 + l16] = (short)(hpk >> 16);
    }
    const float b1m = xm[4 + qh] + hbbm;
    const float hv  = fmaxf(xm[6 + qh] + vb1m, 0.f) * vW2m;
    FENCE();

    // ---- wf layer2, both sites stacked ----
    float wfm;
    {
        const short* hfP = L.hb16[l16 >> 3];
        const bs8 hf0 = *(const bs8*)&hfP[quad * 8];
        const bs8 hf1 = *(const bs8*)&hfP[32 + quad * 8];
        f4 acc0 = {0.f, 0.f, 0.f, 0.f};
        acc0 = MFMA(hf0, LOADB(54), acc0);
        acc0 = MFMA(hf1, LOADB(56), acc0);
        f4 acc1 = {0.f, 0.f, 0.f, 0.f};
        acc1 = MFMA(hf0, LOADB(55), acc1);
        acc1 = MFMA(hf1, LOADB(57), acc1);
        wfm = fabsf((qh ? acc1[0] : acc0[0]) + wfb2m);
    }

    // ---- hall^T = w1_W1^T @ emi^T (A = w1_W1 tiles reused; b64 writes) ----
    #pragma unroll
    for (int mt = 0; mt < 4; ++mt) {
        f4 acc = {0.f, 0.f, 0.f, 0.f};
        acc = MFMA(LOADB(16 + mt),      aab0, acc);
        acc = MFMA(LOADB(16 + 4 + mt),  aab1, acc);
        acc = MFMA(LOADB(16 + 8 + mt),  ag0,  acc);
        acc = MFMA(LOADB(16 + 12 + mt), ag1,  acc);
        const float4 b1v4 = *(const float4*)&w1_b1[mt * 16 + quad * 4];
        uint2 hw;
        hw.x = cvtpk(fmaxf(acc[0] + b1v4.x, 0.f), fmaxf(acc[1] + b1v4.y, 0.f));
        hw.y = cvtpk(fmaxf(acc[2] + b1v4.z, 0.f), fmaxf(acc[3] + b1v4.w, 0.f));
        *(uint2*)&L.scr[0][l16][mt * 16 + quad * 4] = hw;
    }
    FENCE();

    // ---- hypernet L2 + mixing partials (rows = stacked agents) ----
    float pm;
    {
        const bs8 ha0 = *(const bs8*)&L.scr[0][l16][quad * 8];
        const bs8 ha1 = *(const bs8*)&L.scr[0][l16][32 + quad * 8];
        float p0 = 0.f, p1 = 0.f;
        #pragma unroll
        for (int n0t = 0; n0t < 2; ++n0t) {
            f4 acc = {0.f, 0.f, 0.f, 0.f};
            acc = MFMA(ha0, LOADB(32 + n0t), acc);
            acc = MFMA(ha1, LOADB(34 + n0t), acc);
            const float b2v = n0t ? w1b2b : w1b2a;
            float p = qsv4.x * fabsf(acc[0] + b2v) + qsv4.y * fabsf(acc[1] + b2v)
                    + qsv4.z * fabsf(acc[2] + b2v) + qsv4.w * fabsf(acc[3] + b2v);
            if (n0t == 0) p0 = p; else p1 = p;
        }
        p0 += __shfl_xor(p0, 16, 64);
        p1 += __shfl_xor(p1, 16, 64);
        pm = qh ? p1 : p0;
    }

    // ---- elu, mix (+v partial), half-reduce ----
    float hp = pm + b1m;
    hp = (hp > 0.f) ? hp : (__expf(hp) - 1.f);
    float contrib = hp * wfm + hv;
    contrib += __shfl_xor(contrib, 1, 64);
    contrib += __shfl_xor(contrib, 2, 64);
    contrib += __shfl_xor(contrib, 4, 64);
    contrib += __shfl_xor(contrib, 8, 64);
    contrib += __shfl_xor(contrib, 16, 64);
    if ((lane & 31) == 0)
        out[siteA + half] = contrib + vb2;
}

extern "C" void kernel_launch(void* const* d_in, const int* in_sizes, int n_in,
                              void* d_out, int out_size, void* d_ws, size_t ws_size,
                              hipStream_t stream) {
    const float* p[25];
    for (int i = 0; i < 25; ++i) p[i] = (const float*)d_in[i];
    // 0 agent_qs 1 ally 2 enemy 3 W_al 4 b_al 5 W_en 6 b_en 7 Wq 8 bq 9 Wk 10 bk
    // 11 w1_W1 12 w1_b1 13 w1_W2 14 w1_b2 15 wf_W1 16 wf_b1 17 wf_W2 18 wf_b2
    // 19 hb_W 20 hb_b 21 v_W1 22 v_b1 23 v_W2 24 v_b2
    short* fb = (short*)d_ws;   // 58 tiles * 512 bf16 = 59392 B

    qmix_pack<<<58, 64, 0, stream>>>(p[7], p[9], p[10], p[3], p[5],
                                     p[11], p[13], p[15], p[19], p[21], p[17], fb);
    qmix_main<<<BS_ / 4, 128, 0, stream>>>(
        p[0], p[1], p[2], p[4], p[6], p[12], p[14],
        p[16], p[18], p[20], p[22], p[23], p[24],
        fb, (float*)d_out);
}